// Round 1
// baseline (160.847 us; speedup 1.0000x reference)
//
#include <hip/hip_runtime.h>
#include <math.h>

#define B_N   8192
#define D_K   256
#define NGENE 200

typedef short  bf16x8 __attribute__((ext_vector_type(8)));
typedef float  f32x4  __attribute__((ext_vector_type(4)));

// ---- workspace layout (bytes) ----
#define OFF_FNBF    0u          // 8192*256*2 = 4194304
#define OFF_LPART   4194304u    // 16*8192*4  = 524288
#define OFF_LSE     4718592u    // 8192*4
#define OFF_HAS     4751360u    // 8192*4
#define OFF_HIST    4784128u    // 256*4
#define OFF_OFFS    4785152u    // 256*4
#define OFF_CURSOR  4786176u    // 256*4
#define OFF_SORTED  4787200u    // 8192*4
#define OFF_CROSSP  4819968u    // 2048*4
#define OFF_WITHINP 4828160u    // 256*4

__device__ __forceinline__ unsigned short f2bf(float f) {
    unsigned int u = __float_as_uint(f);
    unsigned int r = u + 0x7fffu + ((u >> 16) & 1u);
    return (unsigned short)(r >> 16);
}
__device__ __forceinline__ float bf2f(unsigned short h) {
    return __uint_as_float(((unsigned int)h) << 16);
}

// ---- kernel 1: row L2-normalize -> bf16, plus label histogram ----
__global__ __launch_bounds__(256) void k_normalize(const float* __restrict__ feat,
                                                   const int* __restrict__ lab,
                                                   unsigned short* __restrict__ fnbf,
                                                   int* __restrict__ hist) {
    int wave = threadIdx.x >> 6, lane = threadIdx.x & 63;
    int row  = blockIdx.x * 4 + wave;
    const float4* src = reinterpret_cast<const float4*>(feat + (size_t)row * D_K);
    float4 v = src[lane];
    float ss = v.x * v.x + v.y * v.y + v.z * v.z + v.w * v.w;
#pragma unroll
    for (int m = 1; m < 64; m <<= 1) ss += __shfl_xor(ss, m);
    float rn = 1.0f / sqrtf(ss);
    ushort4 o;
    o.x = f2bf(v.x * rn); o.y = f2bf(v.y * rn);
    o.z = f2bf(v.z * rn); o.w = f2bf(v.w * rn);
    reinterpret_cast<ushort4*>(fnbf + (size_t)row * D_K)[lane] = o;
    if (lane == 0) {
        int lb = lab[row];
        if (lb >= 0 && lb < NGENE) atomicAdd(&hist[lb], 1);
    }
}

// ---- kernel 2: exclusive prefix over gene histogram ----
__global__ __launch_bounds__(256) void k_prefix(const int* __restrict__ hist,
                                                int* __restrict__ offs,
                                                int* __restrict__ cursor) {
    __shared__ int sh[256];
    int t = threadIdx.x;
    int v = (t < NGENE) ? hist[t] : 0;
    sh[t] = v;
    __syncthreads();
#pragma unroll
    for (int d = 1; d < 256; d <<= 1) {
        int x = (t >= d) ? sh[t - d] : 0;
        __syncthreads();
        sh[t] += x;
        __syncthreads();
    }
    int excl = sh[t] - v;
    if (t < NGENE) { offs[t] = excl; cursor[t] = excl; }
}

// ---- kernel 3: scatter row indices grouped by gene ----
__global__ __launch_bounds__(256) void k_scatter(const int* __restrict__ lab,
                                                 int* __restrict__ cursor,
                                                 int* __restrict__ sorted) {
    int i = blockIdx.x * 256 + threadIdx.x;
    int lb = lab[i];
    if (lb >= 0 && lb < NGENE) {
        int pos = atomicAdd(&cursor[lb], 1);
        sorted[pos] = i;
    }
}

// ---- kernel 4: the heavy fused pairwise pass ----
// wave = 64 rows (4 MFMA row tiles), block = 4 waves = 256 rows, sweeping 512 cols
#define MT 4
__global__ __launch_bounds__(256, 2) void k_pairwise(const unsigned short* __restrict__ fnbf,
                                                     const int* __restrict__ lab,
                                                     float* __restrict__ l_part,
                                                     float* __restrict__ cross_part) {
    int wave = threadIdx.x >> 6, lane = threadIdx.x & 63;
    int g16 = lane >> 4, l16 = lane & 15;
    int r0 = blockIdx.x * 256 + wave * 64;
    int j0base = blockIdx.y * 512;

    const bf16x8* fv = reinterpret_cast<const bf16x8*>(fnbf);

    // hoist A fragments: a[t][ks] covers rows [r0+t*16, +16), k = ks*32 + g16*8 .. +8
    bf16x8 a[MT][8];
#pragma unroll
    for (int t = 0; t < MT; ++t)
#pragma unroll
        for (int ks = 0; ks < 8; ++ks)
            a[t][ks] = fv[(r0 + t * 16 + l16) * 32 + ks * 4 + g16];

    // row labels for this lane's accumulator rows
    int rl[MT][4];
#pragma unroll
    for (int t = 0; t < MT; ++t)
#pragma unroll
        for (int r = 0; r < 4; ++r)
            rl[t][r] = lab[r0 + t * 16 + g16 * 4 + r];

    float lsum[MT][4];
#pragma unroll
    for (int t = 0; t < MT; ++t)
#pragma unroll
        for (int r = 0; r < 4; ++r) lsum[t][r] = 0.f;
    float csum = 0.f;

    for (int step = 0; step < 32; ++step) {
        int j0 = j0base + step * 16;
        bf16x8 b[8];
#pragma unroll
        for (int ks = 0; ks < 8; ++ks)
            b[ks] = fv[(j0 + l16) * 32 + ks * 4 + g16];

        f32x4 acc[MT];
#pragma unroll
        for (int t = 0; t < MT; ++t) acc[t] = (f32x4){0.f, 0.f, 0.f, 0.f};
#pragma unroll
        for (int ks = 0; ks < 8; ++ks)
#pragma unroll
            for (int t = 0; t < MT; ++t)
                acc[t] = __builtin_amdgcn_mfma_f32_16x16x32_bf16(a[t][ks], b[ks], acc[t], 0, 0, 0);

        int cl = lab[j0 + l16];
#pragma unroll
        for (int t = 0; t < MT; ++t)
#pragma unroll
            for (int r = 0; r < 4; ++r) {
                float s = 2.0f * acc[t][r];
                bool neg = (rl[t][r] != cl);
                float e = __expf(s);
                float cr = fmaxf(s - 0.1f, 0.0f);
                lsum[t][r] += neg ? e : 0.0f;
                csum      += neg ? cr : 0.0f;
            }
    }

    // reduce masked-exp sums across the 16 lanes sharing each row
#pragma unroll
    for (int t = 0; t < MT; ++t)
#pragma unroll
        for (int r = 0; r < 4; ++r) {
            float v = lsum[t][r];
            v += __shfl_xor(v, 1); v += __shfl_xor(v, 2);
            v += __shfl_xor(v, 4); v += __shfl_xor(v, 8);
            if (l16 == 0)
                l_part[blockIdx.y * B_N + r0 + t * 16 + g16 * 4 + r] = v;
        }

    float c = csum;
#pragma unroll
    for (int m = 1; m < 64; m <<= 1) c += __shfl_xor(c, m);
    if (lane == 0)
        cross_part[(blockIdx.y * gridDim.x + blockIdx.x) * 4 + wave] = c;
}

// ---- kernel 5: combine per-chunk lse partials ----
__global__ __launch_bounds__(256) void k_combine(const float* __restrict__ l_part,
                                                 float* __restrict__ lse,
                                                 int* __restrict__ has) {
    int row = blockIdx.x * 256 + threadIdx.x;
    float s = 0.f;
#pragma unroll
    for (int c = 0; c < 16; ++c) s += l_part[c * B_N + row];
    int h = (s > 0.f) ? 1 : 0;
    lse[row] = h ? logf(s) : 0.f;
    has[row] = h;
}

// ---- kernel 6: within-gene pair loss (sparse recompute) ----
__global__ __launch_bounds__(256) void k_within(const unsigned short* __restrict__ fnbf,
                                                const int* __restrict__ lab,
                                                const int* __restrict__ hist,
                                                const int* __restrict__ offs,
                                                const int* __restrict__ sorted,
                                                const float* __restrict__ lse,
                                                const int* __restrict__ has,
                                                float* __restrict__ within_part) {
    int g = blockIdx.x;
    int n = hist[g], start = offs[g];
    int P = n * (n - 1) / 2;
    float sum = 0.f;
    const bf16x8* fv = reinterpret_cast<const bf16x8*>(fnbf);
    for (int p = threadIdx.x; p < P; p += 256) {
        int aa = 0, pp = p, span = n - 1;
        while (pp >= span) { pp -= span; ++aa; --span; }
        int bb = aa + 1 + pp;
        int i = sorted[start + aa], j = sorted[start + bb];
        int anchor = i < j ? i : j;
        int other  = i < j ? j : i;
        if (lab[anchor] == -1 || !has[anchor]) continue;
        const bf16x8* pa = fv + anchor * 32;
        const bf16x8* pb = fv + other * 32;
        float d = 0.f;
#pragma unroll
        for (int k = 0; k < 32; ++k) {
            bf16x8 va = pa[k], vb = pb[k];
#pragma unroll
            for (int e = 0; e < 8; ++e)
                d += bf2f((unsigned short)va[e]) * bf2f((unsigned short)vb[e]);
        }
        float s = 2.0f * d;
        float x = lse[anchor] - s;
        sum += fmaxf(x, 0.f) + log1pf(__expf(-fabsf(x)));
    }
    __shared__ float sh[256];
    sh[threadIdx.x] = sum;
    __syncthreads();
#pragma unroll
    for (int d = 128; d > 0; d >>= 1) {
        if (threadIdx.x < d) sh[threadIdx.x] += sh[threadIdx.x + d];
        __syncthreads();
    }
    if (threadIdx.x == 0) within_part[g] = sh[0];
}

// ---- kernel 7: final reduction + outputs ----
__global__ __launch_bounds__(256) void k_finalize(const float* __restrict__ cross_part,
                                                  const float* __restrict__ within_part,
                                                  const int* __restrict__ hist,
                                                  float* __restrict__ out) {
    __shared__ float shc[256];
    __shared__ float shw[256];
    __shared__ long long shs[256];
    int t = threadIdx.x;
    float cs = 0.f;
    for (int i = t; i < 2048; i += 256) cs += cross_part[i];
    float wv = (t < NGENE) ? within_part[t] : 0.f;
    long long s2 = 0;
    if (t < NGENE) { long long h = hist[t]; s2 = h * h; }
    shc[t] = cs; shw[t] = wv; shs[t] = s2;
    __syncthreads();
#pragma unroll
    for (int d = 128; d > 0; d >>= 1) {
        if (t < d) { shc[t] += shc[t + d]; shw[t] += shw[t + d]; shs[t] += shs[t + d]; }
        __syncthreads();
    }
    if (t == 0) {
        long long S  = shs[0];
        long long nw = S - (long long)B_N;
        long long nc = (long long)B_N * (long long)B_N - S;
        float cross_loss = (nc > 0) ? (shc[0] / (float)(nc > 1 ? nc : 1)) : 0.f;
        float within     = shw[0];
        float total      = within + 0.5f * cross_loss;
        out[0] = total;
        out[1] = within;
        out[2] = cross_loss;
        out[3] = (float)nw;
        out[4] = (float)nc;
    }
}

extern "C" void kernel_launch(void* const* d_in, const int* in_sizes, int n_in,
                              void* d_out, int out_size, void* d_ws, size_t ws_size,
                              hipStream_t stream) {
    const float* feat = (const float*)d_in[0];
    const int*   lab  = (const int*)d_in[1];
    float* out = (float*)d_out;
    char* ws = (char*)d_ws;

    unsigned short* fnbf   = (unsigned short*)(ws + OFF_FNBF);
    float* l_part          = (float*)(ws + OFF_LPART);
    float* lse             = (float*)(ws + OFF_LSE);
    int*   has             = (int*)(ws + OFF_HAS);
    int*   hist            = (int*)(ws + OFF_HIST);
    int*   offs            = (int*)(ws + OFF_OFFS);
    int*   cursor          = (int*)(ws + OFF_CURSOR);
    int*   sorted          = (int*)(ws + OFF_SORTED);
    float* cross_part      = (float*)(ws + OFF_CROSSP);
    float* within_part     = (float*)(ws + OFF_WITHINP);

    hipMemsetAsync(hist, 0, 256 * sizeof(int), stream);

    k_normalize<<<B_N / 4, 256, 0, stream>>>(feat, lab, fnbf, hist);
    k_prefix<<<1, 256, 0, stream>>>(hist, offs, cursor);
    k_scatter<<<B_N / 256, 256, 0, stream>>>(lab, cursor, sorted);
    k_pairwise<<<dim3(B_N / 256, B_N / 512), 256, 0, stream>>>(fnbf, lab, l_part, cross_part);
    k_combine<<<B_N / 256, 256, 0, stream>>>(l_part, lse, has);
    k_within<<<NGENE, 256, 0, stream>>>(fnbf, lab, hist, offs, sorted, lse, has, within_part);
    k_finalize<<<1, 256, 0, stream>>>(cross_part, within_part, hist, out);
}